// Round 1
// baseline (3283.993 us; speedup 1.0000x reference)
//
#include <hip/hip_runtime.h>
#include <hip/hip_bf16.h>

typedef __hip_bfloat16 bf16;

// Problem constants
#define BB    4
#define LQ    4096
#define LIN   16464
#define DM    768
#define NH    12
#define HD    64
// Levels: (112,112),(56,56),(28,28); starts 0,12544,15680; query grid 64x64

// ---------------------------------------------------------------------------
// LayerNorm over last dim 768, fp32 in -> bf16 out
// ---------------------------------------------------------------------------
__global__ __launch_bounds__(256) void ln_kernel(
    const float* __restrict__ x, const float* __restrict__ g,
    const float* __restrict__ beta, bf16* __restrict__ y)
{
    int r = blockIdx.x;
    const float* xr = x + (size_t)r * DM;
    int t = threadIdx.x;
    float v0 = xr[t], v1 = xr[t + 256], v2 = xr[t + 512];
    float s  = v0 + v1 + v2;
    float ss = v0 * v0 + v1 * v1 + v2 * v2;
    #pragma unroll
    for (int o = 32; o > 0; o >>= 1) {
        s  += __shfl_down(s, o);
        ss += __shfl_down(ss, o);
    }
    __shared__ float sh1[4], sh2[4];
    int w = t >> 6, lane = t & 63;
    if (lane == 0) { sh1[w] = s; sh2[w] = ss; }
    __syncthreads();
    if (t == 0) {
        float a = sh1[0] + sh1[1] + sh1[2] + sh1[3];
        float b = sh2[0] + sh2[1] + sh2[2] + sh2[3];
        float mean = a * (1.f / DM);
        float var  = b * (1.f / DM) - mean * mean;
        sh1[0] = mean;
        sh2[0] = rsqrtf(var + 1e-6f);
    }
    __syncthreads();
    float mean = sh1[0], inv = sh2[0];
    bf16* yr = y + (size_t)r * DM;
    yr[t]       = __float2bfloat16((v0 - mean) * inv * g[t]       + beta[t]);
    yr[t + 256] = __float2bfloat16((v1 - mean) * inv * g[t + 256] + beta[t + 256]);
    yr[t + 512] = __float2bfloat16((v2 - mean) * inv * g[t + 512] + beta[t + 512]);
}

// ---------------------------------------------------------------------------
// SIMT tiled GEMM: C(M,N) = A(M,768)[bf16] @ W(768,N)[f32] + bias
// mode 0: store bf16; mode 1: store f32; mode 2: f32 out = resid + gamma*(acc+bias)
// M must be a multiple of 64. N guarded.
// ---------------------------------------------------------------------------
__global__ __launch_bounds__(256) void gemm_kernel(
    const bf16*  __restrict__ A,
    const float* __restrict__ W,
    const float* __restrict__ bias,
    void*        __restrict__ C,
    const float* __restrict__ resid,
    const float* __restrict__ gamma,
    int M, int N, int mode)
{
    __shared__ float As[16][65];
    __shared__ float Bs[16][65];
    int bm = blockIdx.y * 64, bn = blockIdx.x * 64;
    int tid = threadIdx.x;
    int tm = (tid >> 4) << 2;
    int tn = (tid & 15) << 2;
    float acc[4][4] = {{0.f}};
    for (int k0 = 0; k0 < DM; k0 += 16) {
        #pragma unroll
        for (int i = 0; i < 4; i++) {
            int e = (tid << 2) + i;
            int r = e >> 4, c = e & 15;
            As[c][r] = __bfloat162float(A[(size_t)(bm + r) * DM + k0 + c]);
        }
        #pragma unroll
        for (int i = 0; i < 4; i++) {
            int e = (tid << 2) + i;
            int r = e >> 6, c = e & 63;
            int col = bn + c;
            Bs[r][c] = (col < N) ? W[(size_t)(k0 + r) * N + col] : 0.f;
        }
        __syncthreads();
        #pragma unroll
        for (int kk = 0; kk < 16; kk++) {
            float a[4], b[4];
            #pragma unroll
            for (int i = 0; i < 4; i++) a[i] = As[kk][tm + i];
            #pragma unroll
            for (int j = 0; j < 4; j++) b[j] = Bs[kk][tn + j];
            #pragma unroll
            for (int i = 0; i < 4; i++)
                #pragma unroll
                for (int j = 0; j < 4; j++)
                    acc[i][j] = fmaf(a[i], b[j], acc[i][j]);
        }
        __syncthreads();
    }
    #pragma unroll
    for (int i = 0; i < 4; i++) {
        int r = bm + tm + i;
        #pragma unroll
        for (int j = 0; j < 4; j++) {
            int c = bn + tn + j;
            if (c < N) {
                float v = acc[i][j] + bias[c];
                size_t idx = (size_t)r * N + c;
                if (mode == 0)      ((bf16*)C)[idx]  = __float2bfloat16(v);
                else if (mode == 1) ((float*)C)[idx] = v;
                else                ((float*)C)[idx] = resid[idx] + gamma[c] * v;
            }
        }
    }
}

// ---------------------------------------------------------------------------
// Deformable sampling: per (b,q,h) unit of 64 lanes (lane = channel d).
// value (B,LIN,NH,HD) bf16; off (B,LQ,288) f32; logits (B,LQ,144) f32.
// attn out (B,LQ,768) bf16.
// ---------------------------------------------------------------------------
__device__ __forceinline__ float fetchv(const bf16* __restrict__ value,
                                        int basec, int wl, int y, int x,
                                        int h, int d)
{
    if (x < 0 || x >= wl || y < 0 || y >= wl) return 0.f;
    return __bfloat162float(value[(((size_t)(basec + y * wl + x)) * NH + h) * HD + d]);
}

__global__ __launch_bounds__(256) void sample_kernel(
    const bf16*  __restrict__ value,
    const float* __restrict__ off,
    const float* __restrict__ logits,
    bf16*        __restrict__ attn)
{
    int unit = (blockIdx.x << 2) + (threadIdx.x >> 6); // (b*LQ+q)*NH + h
    int d = threadIdx.x & 63;
    int h  = unit % NH;
    int bq = unit / NH;
    int q = bq & (LQ - 1);
    int b = bq >> 12;

    const int sl[3] = {0, 12544, 15680};
    const int hw[3] = {112, 56, 28};

    // softmax over 12 (redundant per lane; broadcast loads)
    const float* lg = logits + (size_t)bq * (NH * 12) + h * 12;
    float l[12];
    float mx = -1e30f;
    #pragma unroll
    for (int i = 0; i < 12; i++) { l[i] = lg[i]; mx = fmaxf(mx, l[i]); }
    float den = 0.f;
    #pragma unroll
    for (int i = 0; i < 12; i++) { l[i] = __expf(l[i] - mx); den += l[i]; }
    float rden = 1.f / den;

    float rx = ((q & 63) + 0.5f) * (1.f / 64.f);
    float ry = ((q >> 6) + 0.5f) * (1.f / 64.f);

    const float* ob = off + (size_t)bq * (NH * 24) + h * 24;
    float acc = 0.f;
    #pragma unroll
    for (int lv = 0; lv < 3; lv++) {
        int wl = hw[lv];
        int basec = b * LIN + sl[lv];
        #pragma unroll
        for (int p = 0; p < 4; p++) {
            float ox = ob[lv * 8 + p * 2 + 0];
            float oy = ob[lv * 8 + p * 2 + 1];
            // (rx + ox/wl)*wl - 0.5 == rx*wl + ox - 0.5 (levels are square)
            float x = rx * wl + ox - 0.5f;
            float y = ry * wl + oy - 0.5f;
            float xf = floorf(x), yf = floorf(y);
            float wx = x - xf, wy = y - yf;
            int x0 = (int)xf, y0 = (int)yf;
            float v00 = fetchv(value, basec, wl, y0,     x0,     h, d);
            float v01 = fetchv(value, basec, wl, y0,     x0 + 1, h, d);
            float v10 = fetchv(value, basec, wl, y0 + 1, x0,     h, d);
            float v11 = fetchv(value, basec, wl, y0 + 1, x0 + 1, h, d);
            float sv = v00 * (1.f - wx) * (1.f - wy) + v01 * wx * (1.f - wy)
                     + v10 * (1.f - wx) * wy         + v11 * wx * wy;
            acc += (l[lv * 4 + p] * rden) * sv;
        }
    }
    attn[(size_t)bq * DM + h * HD + d] = __float2bfloat16(acc);
}

// ---------------------------------------------------------------------------
extern "C" void kernel_launch(void* const* d_in, const int* in_sizes, int n_in,
                              void* d_out, int out_size, void* d_ws, size_t ws_size,
                              hipStream_t stream)
{
    const float* query  = (const float*)d_in[0];
    const float* feat   = (const float*)d_in[1];
    const float* ln_q_g = (const float*)d_in[2];
    const float* ln_q_b = (const float*)d_in[3];
    const float* ln_f_g = (const float*)d_in[4];
    const float* ln_f_b = (const float*)d_in[5];
    const float* W_off  = (const float*)d_in[6];
    const float* b_off  = (const float*)d_in[7];
    const float* W_attn = (const float*)d_in[8];
    const float* b_attn = (const float*)d_in[9];
    const float* W_val  = (const float*)d_in[10];
    const float* b_val  = (const float*)d_in[11];
    const float* W_out  = (const float*)d_in[12];
    const float* b_out  = (const float*)d_in[13];
    const float* gamma  = (const float*)d_in[14];
    float* out = (float*)d_out;

    char* ws = (char*)d_ws;
    const int M_F = BB * LIN;   // 65856
    const int M_Q = BB * LQ;    // 16384

    // Workspace layout (bytes); off/logits/attn alias f_ln (dead after value GEMM)
    bf16*  value  = (bf16*)(ws);                                    // 101,154,816
    bf16*  q_ln   = (bf16*)(ws + 101154816);                        //  25,165,824
    bf16*  f_ln   = (bf16*)(ws + 126320640);                        // 101,154,816
    float* offb   = (float*)(ws + 126320640);                       //  18,874,368
    float* logits = (float*)(ws + 145195008);                       //   9,437,184
    bf16*  attn   = (bf16*)(ws + 154632192);                        //  25,165,824
    // total needed: 227,475,456 bytes

    // 1. LayerNorms
    ln_kernel<<<M_F, 256, 0, stream>>>(feat, ln_f_g, ln_f_b, f_ln);
    ln_kernel<<<M_Q, 256, 0, stream>>>(query, ln_q_g, ln_q_b, q_ln);

    // 2. value = f_ln @ W_val + b_val  (bf16 out)
    gemm_kernel<<<dim3(DM / 64, M_F / 64), 256, 0, stream>>>(
        f_ln, W_val, b_val, value, nullptr, nullptr, M_F, DM, 0);

    // 3. off = q_ln @ W_off + b_off  (f32 out)
    gemm_kernel<<<dim3(5, M_Q / 64), 256, 0, stream>>>(
        q_ln, W_off, b_off, offb, nullptr, nullptr, M_Q, 288, 1);

    // 4. logits = q_ln @ W_attn + b_attn  (f32 out)
    gemm_kernel<<<dim3(3, M_Q / 64), 256, 0, stream>>>(
        q_ln, W_attn, b_attn, logits, nullptr, nullptr, M_Q, 144, 1);

    // 5. deformable sampling -> attn (bf16)
    sample_kernel<<<(M_Q * NH) / 4, 256, 0, stream>>>(value, offb, logits, attn);

    // 6. out = query + gamma * (attn @ W_out + b_out)
    gemm_kernel<<<dim3(DM / 64, M_Q / 64), 256, 0, stream>>>(
        attn, W_out, b_out, out, query, gamma, M_Q, DM, 2);
}

// Round 2
// 1453.692 us; speedup vs baseline: 2.2591x; 2.2591x over previous
//
#include <hip/hip_runtime.h>
#include <hip/hip_bf16.h>

typedef __hip_bfloat16 bf16;

// Problem constants
#define BB    4
#define LQ    4096
#define LIN   16464
#define DM    768
#define NH    12
#define HD    64
#define K_DIM 768
// Levels: (112,112),(56,56),(28,28); starts 0,12544,15680; query grid 64x64

typedef __attribute__((ext_vector_type(8))) __bf16 bfrag;
typedef __attribute__((ext_vector_type(4))) float  ffrag;

// ---------------------------------------------------------------------------
// async global->LDS 16B per lane
// ---------------------------------------------------------------------------
__device__ __forceinline__ void g2l16(const void* g, void* l) {
    __builtin_amdgcn_global_load_lds(
        (const __attribute__((address_space(1))) void*)g,
        (__attribute__((address_space(3))) void*)l, 16, 0, 0);
}

// ---------------------------------------------------------------------------
// LayerNorm over last dim 768, fp32 in -> bf16 out
// ---------------------------------------------------------------------------
__global__ __launch_bounds__(256) void ln_kernel(
    const float* __restrict__ x, const float* __restrict__ g,
    const float* __restrict__ beta, bf16* __restrict__ y)
{
    int r = blockIdx.x;
    const float* xr = x + (size_t)r * DM;
    int t = threadIdx.x;
    float v0 = xr[t], v1 = xr[t + 256], v2 = xr[t + 512];
    float s  = v0 + v1 + v2;
    float ss = v0 * v0 + v1 * v1 + v2 * v2;
    #pragma unroll
    for (int o = 32; o > 0; o >>= 1) {
        s  += __shfl_down(s, o);
        ss += __shfl_down(ss, o);
    }
    __shared__ float sh1[4], sh2[4];
    int w = t >> 6, lane = t & 63;
    if (lane == 0) { sh1[w] = s; sh2[w] = ss; }
    __syncthreads();
    if (t == 0) {
        float a = sh1[0] + sh1[1] + sh1[2] + sh1[3];
        float b = sh2[0] + sh2[1] + sh2[2] + sh2[3];
        float mean = a * (1.f / DM);
        float var  = b * (1.f / DM) - mean * mean;
        sh1[0] = mean;
        sh2[0] = rsqrtf(var + 1e-6f);
    }
    __syncthreads();
    float mean = sh1[0], inv = sh2[0];
    bf16* yr = y + (size_t)r * DM;
    yr[t]       = __float2bfloat16((v0 - mean) * inv * g[t]       + beta[t]);
    yr[t + 256] = __float2bfloat16((v1 - mean) * inv * g[t + 256] + beta[t + 256]);
    yr[t + 512] = __float2bfloat16((v2 - mean) * inv * g[t + 512] + beta[t + 512]);
}

// ---------------------------------------------------------------------------
// Cast + transpose weights: W (768 x N f32, row-major) -> Wt (Npad x 768 bf16)
// rows n >= N are zero-filled. Grid: (Npad/32, 768/32), block 256.
// ---------------------------------------------------------------------------
__global__ __launch_bounds__(256) void cast_transpose(
    const float* __restrict__ W, bf16* __restrict__ Wt, int N)
{
    __shared__ float t[32][33];
    int n0 = blockIdx.x * 32, k0 = blockIdx.y * 32;
    int tx = threadIdx.x & 31, ty = threadIdx.x >> 5;  // ty 0..7
    #pragma unroll
    for (int i = 0; i < 4; i++) {
        int k = k0 + ty + i * 8;
        int n = n0 + tx;
        t[ty + i * 8][tx] = (n < N) ? W[(size_t)k * N + n] : 0.f;
    }
    __syncthreads();
    #pragma unroll
    for (int i = 0; i < 4; i++) {
        int n = n0 + ty + i * 8;
        Wt[(size_t)n * K_DIM + k0 + tx] = __float2bfloat16(t[tx][ty + i * 8]);
    }
}

// ---------------------------------------------------------------------------
// MFMA bf16 GEMM: C(M,N) = A(M,768) @ Wt(N,768)^T + bias
// 128x128 tile, 256 threads (4 waves, 2x2 of 64x64), K-step 32.
// mode 0: bf16 store; mode 1: f32 store; mode 2: f32 = resid + gamma*(acc+bias)
// ---------------------------------------------------------------------------
__global__ __launch_bounds__(256) void mfma_gemm(
    const bf16*  __restrict__ A,
    const bf16*  __restrict__ Bt,
    const float* __restrict__ bias,
    void*        __restrict__ C,
    const float* __restrict__ resid,
    const float* __restrict__ gamma,
    int M, int N, int mode)
{
    __shared__ __align__(16) char lds[16384];
    char* As = lds;
    char* Bs = lds + 8192;

    int tid  = threadIdx.x;
    int lane = tid & 63;
    int bm = blockIdx.y * 128, bn = blockIdx.x * 128;
    int wave = tid >> 6;
    int wr = (wave & 1) * 64, wc = (wave >> 1) * 64;

    ffrag acc[4][4] = {};

    // staging: 512 chunks of 16B per tile; thread covers chunks tid, tid+256
    int c0 = tid, c1 = tid + 256;
    int r0 = c0 >> 2, kb0 = (c0 & 3) * 8;
    int r1 = c1 >> 2, kb1 = (c1 & 3) * 8;
    int ra0 = min(bm + r0, M - 1), ra1 = min(bm + r1, M - 1);
    const bf16* gA0 = A  + (size_t)ra0 * K_DIM + kb0;
    const bf16* gA1 = A  + (size_t)ra1 * K_DIM + kb1;
    const bf16* gB0 = Bt + (size_t)(bn + r0) * K_DIM + kb0;
    const bf16* gB1 = Bt + (size_t)(bn + r1) * K_DIM + kb1;

    int mrow = lane & 15;
    int kq   = (lane >> 4) * 8;

    for (int k0 = 0; k0 < K_DIM; k0 += 32) {
        g2l16(gA0 + k0, As + c0 * 16);
        g2l16(gA1 + k0, As + c1 * 16);
        g2l16(gB0 + k0, Bs + c0 * 16);
        g2l16(gB1 + k0, Bs + c1 * 16);
        __syncthreads();
        bfrag a[4], b[4];
        #pragma unroll
        for (int t = 0; t < 4; t++) {
            a[t] = *(const bfrag*)(As + ((wr + t * 16 + mrow) * 32 + kq) * 2);
            b[t] = *(const bfrag*)(Bs + ((wc + t * 16 + mrow) * 32 + kq) * 2);
        }
        #pragma unroll
        for (int i = 0; i < 4; i++)
            #pragma unroll
            for (int j = 0; j < 4; j++)
                acc[i][j] = __builtin_amdgcn_mfma_f32_16x16x32_bf16(
                    a[i], b[j], acc[i][j], 0, 0, 0);
        __syncthreads();
    }

    // epilogue: C/D layout col = lane&15, row = (lane>>4)*4 + reg
    int q4 = (lane >> 4) * 4;
    #pragma unroll
    for (int i = 0; i < 4; i++) {
        #pragma unroll
        for (int r = 0; r < 4; r++) {
            int rg = bm + wr + i * 16 + q4 + r;
            if (rg < M) {
                #pragma unroll
                for (int j = 0; j < 4; j++) {
                    int cg = bn + wc + j * 16 + mrow;
                    if (cg < N) {
                        float v = acc[i][j][r] + bias[cg];
                        size_t idx = (size_t)rg * N + cg;
                        if (mode == 0)      ((bf16*)C)[idx]  = __float2bfloat16(v);
                        else if (mode == 1) ((float*)C)[idx] = v;
                        else ((float*)C)[idx] = resid[idx] + gamma[cg] * v;
                    }
                }
            }
        }
    }
}

// ---------------------------------------------------------------------------
// Deformable sampling: per (b,q,h) unit of 64 lanes (lane = channel d).
// ---------------------------------------------------------------------------
__device__ __forceinline__ float fetchv(const bf16* __restrict__ value,
                                        int basec, int wl, int y, int x,
                                        int h, int d)
{
    if (x < 0 || x >= wl || y < 0 || y >= wl) return 0.f;
    return __bfloat162float(value[(((size_t)(basec + y * wl + x)) * NH + h) * HD + d]);
}

__global__ __launch_bounds__(256) void sample_kernel(
    const bf16*  __restrict__ value,
    const float* __restrict__ off,
    const float* __restrict__ logits,
    bf16*        __restrict__ attn)
{
    int unit = (blockIdx.x << 2) + (threadIdx.x >> 6); // (b*LQ+q)*NH + h
    int d = threadIdx.x & 63;
    int h  = unit % NH;
    int bq = unit / NH;
    int q = bq & (LQ - 1);
    int b = bq >> 12;

    const int sl[3] = {0, 12544, 15680};
    const int hw[3] = {112, 56, 28};

    const float* lg = logits + (size_t)bq * (NH * 12) + h * 12;
    float l[12];
    float mx = -1e30f;
    #pragma unroll
    for (int i = 0; i < 12; i++) { l[i] = lg[i]; mx = fmaxf(mx, l[i]); }
    float den = 0.f;
    #pragma unroll
    for (int i = 0; i < 12; i++) { l[i] = __expf(l[i] - mx); den += l[i]; }
    float rden = 1.f / den;

    float rx = ((q & 63) + 0.5f) * (1.f / 64.f);
    float ry = ((q >> 6) + 0.5f) * (1.f / 64.f);

    const float* ob = off + (size_t)bq * (NH * 24) + h * 24;
    float acc = 0.f;
    #pragma unroll
    for (int lv = 0; lv < 3; lv++) {
        int wl = hw[lv];
        int basec = b * LIN + sl[lv];
        #pragma unroll
        for (int p = 0; p < 4; p++) {
            float ox = ob[lv * 8 + p * 2 + 0];
            float oy = ob[lv * 8 + p * 2 + 1];
            float x = rx * wl + ox - 0.5f;
            float y = ry * wl + oy - 0.5f;
            float xf = floorf(x), yf = floorf(y);
            float wx = x - xf, wy = y - yf;
            int x0 = (int)xf, y0 = (int)yf;
            float v00 = fetchv(value, basec, wl, y0,     x0,     h, d);
            float v01 = fetchv(value, basec, wl, y0,     x0 + 1, h, d);
            float v10 = fetchv(value, basec, wl, y0 + 1, x0,     h, d);
            float v11 = fetchv(value, basec, wl, y0 + 1, x0 + 1, h, d);
            float sv = v00 * (1.f - wx) * (1.f - wy) + v01 * wx * (1.f - wy)
                     + v10 * (1.f - wx) * wy         + v11 * wx * wy;
            acc += (l[lv * 4 + p] * rden) * sv;
        }
    }
    attn[(size_t)bq * DM + h * HD + d] = __float2bfloat16(acc);
}

// ---------------------------------------------------------------------------
extern "C" void kernel_launch(void* const* d_in, const int* in_sizes, int n_in,
                              void* d_out, int out_size, void* d_ws, size_t ws_size,
                              hipStream_t stream)
{
    const float* query  = (const float*)d_in[0];
    const float* feat   = (const float*)d_in[1];
    const float* ln_q_g = (const float*)d_in[2];
    const float* ln_q_b = (const float*)d_in[3];
    const float* ln_f_g = (const float*)d_in[4];
    const float* ln_f_b = (const float*)d_in[5];
    const float* W_off  = (const float*)d_in[6];
    const float* b_off  = (const float*)d_in[7];
    const float* W_attn = (const float*)d_in[8];
    const float* b_attn = (const float*)d_in[9];
    const float* W_val  = (const float*)d_in[10];
    const float* b_val  = (const float*)d_in[11];
    const float* W_out  = (const float*)d_in[12];
    const float* b_out  = (const float*)d_in[13];
    const float* gamma  = (const float*)d_in[14];
    float* out = (float*)d_out;

    char* ws = (char*)d_ws;
    char* od = (char*)d_out;
    const int M_F = BB * LIN;   // 65856
    const int M_Q = BB * LQ;    // 16384

    // ws layout (total 227,475,456 B == round-1 proven footprint):
    //   [0, 101,154,816)           value bf16 (65856 x 768)
    //   [101,154,816, 202,309,632) f_ln bf16 (65856 x 768); after value GEMM:
    //       Wt_out bf16 (768 x 768) at 101,154,816
    //   [202,309,632, 227,475,456) q_ln bf16 (16384 x 768); attn overlays it
    //       after the off/logit GEMMs complete
    bf16*  value  = (bf16*)(ws);
    bf16*  f_ln   = (bf16*)(ws + 101154816);
    bf16*  Wt_out = (bf16*)(ws + 101154816);
    bf16*  q_ln   = (bf16*)(ws + 202309632);
    bf16*  attn   = (bf16*)(ws + 202309632);

    // d_out doubles as scratch (50,331,648 B; all dead before final GEMM):
    //   [0, 1,179,648)            Wt_val bf16 (768 x 768)
    //   [1,179,648, 1,769,472)    Wt_off bf16 (384 x 768, zero-padded)
    //   [1,769,472, 2,162,688)    Wt_attn bf16 (256 x 768, zero-padded)
    //   [2,162,688, 21,037,056)   offb f32 (16384 x 288)
    //   [21,037,056, 30,474,240)  logits f32 (16384 x 144)
    bf16*  Wt_val  = (bf16*)(od);
    bf16*  Wt_off  = (bf16*)(od + 1179648);
    bf16*  Wt_attn = (bf16*)(od + 1769472);
    float* offb    = (float*)(od + 2162688);
    float* logits  = (float*)(od + 21037056);

    // 1. weight cast/transpose (Wt_out deferred until f_ln region is dead)
    cast_transpose<<<dim3(768 / 32, 24), 256, 0, stream>>>(W_val,  Wt_val,  768);
    cast_transpose<<<dim3(384 / 32, 24), 256, 0, stream>>>(W_off,  Wt_off,  288);
    cast_transpose<<<dim3(256 / 32, 24), 256, 0, stream>>>(W_attn, Wt_attn, 144);

    // 2. LayerNorms
    ln_kernel<<<M_F, 256, 0, stream>>>(feat, ln_f_g, ln_f_b, f_ln);
    ln_kernel<<<M_Q, 256, 0, stream>>>(query, ln_q_g, ln_q_b, q_ln);

    // 3. value = f_ln @ W_val + b_val (bf16)
    mfma_gemm<<<dim3(6, (M_F + 127) / 128), 256, 0, stream>>>(
        f_ln, Wt_val, b_val, value, nullptr, nullptr, M_F, DM, 0);

    // 4. Wt_out cast into f_ln's (now dead) region
    cast_transpose<<<dim3(768 / 32, 24), 256, 0, stream>>>(W_out, Wt_out, 768);

    // 5. off = q_ln @ W_off + b_off (f32)
    mfma_gemm<<<dim3(3, M_Q / 128), 256, 0, stream>>>(
        q_ln, Wt_off, b_off, offb, nullptr, nullptr, M_Q, 288, 1);

    // 6. logits = q_ln @ W_attn + b_attn (f32)
    mfma_gemm<<<dim3(2, M_Q / 128), 256, 0, stream>>>(
        q_ln, Wt_attn, b_attn, logits, nullptr, nullptr, M_Q, 144, 1);

    // 7. deformable sampling -> attn (bf16)
    sample_kernel<<<(M_Q * NH) / 4, 256, 0, stream>>>(value, offb, logits, attn);

    // 8. out = query + gamma * (attn @ W_out + b_out)
    mfma_gemm<<<dim3(6, M_Q / 128), 256, 0, stream>>>(
        attn, Wt_out, b_out, out, query, gamma, M_Q, DM, 2);
}

// Round 3
// 825.429 us; speedup vs baseline: 3.9785x; 1.7611x over previous
//
#include <hip/hip_runtime.h>
#include <hip/hip_bf16.h>

typedef __hip_bfloat16 bf16;

// Problem constants
#define BB    4
#define LQ    4096
#define LIN   16464
#define DM    768
#define NH    12
#define HD    64
#define K_DIM 768
// Levels: (112,112),(56,56),(28,28); starts 0,12544,15680; query grid 64x64

typedef __attribute__((ext_vector_type(8))) __bf16 bfrag;
typedef __attribute__((ext_vector_type(4))) float  ffrag;

// ---------------------------------------------------------------------------
// async global->LDS 16B per lane
// ---------------------------------------------------------------------------
__device__ __forceinline__ void g2l16(const void* g, void* l) {
    __builtin_amdgcn_global_load_lds(
        (const __attribute__((address_space(1))) void*)g,
        (__attribute__((address_space(3))) void*)l, 16, 0, 0);
}

// ---------------------------------------------------------------------------
// LayerNorm over last dim 768, fp32 in -> bf16 out
// ---------------------------------------------------------------------------
__global__ __launch_bounds__(256) void ln_kernel(
    const float* __restrict__ x, const float* __restrict__ g,
    const float* __restrict__ beta, bf16* __restrict__ y)
{
    int r = blockIdx.x;
    const float* xr = x + (size_t)r * DM;
    int t = threadIdx.x;
    float v0 = xr[t], v1 = xr[t + 256], v2 = xr[t + 512];
    float s  = v0 + v1 + v2;
    float ss = v0 * v0 + v1 * v1 + v2 * v2;
    #pragma unroll
    for (int o = 32; o > 0; o >>= 1) {
        s  += __shfl_down(s, o);
        ss += __shfl_down(ss, o);
    }
    __shared__ float sh1[4], sh2[4];
    int w = t >> 6, lane = t & 63;
    if (lane == 0) { sh1[w] = s; sh2[w] = ss; }
    __syncthreads();
    if (t == 0) {
        float a = sh1[0] + sh1[1] + sh1[2] + sh1[3];
        float b = sh2[0] + sh2[1] + sh2[2] + sh2[3];
        float mean = a * (1.f / DM);
        float var  = b * (1.f / DM) - mean * mean;
        sh1[0] = mean;
        sh2[0] = rsqrtf(var + 1e-6f);
    }
    __syncthreads();
    float mean = sh1[0], inv = sh2[0];
    bf16* yr = y + (size_t)r * DM;
    yr[t]       = __float2bfloat16((v0 - mean) * inv * g[t]       + beta[t]);
    yr[t + 256] = __float2bfloat16((v1 - mean) * inv * g[t + 256] + beta[t + 256]);
    yr[t + 512] = __float2bfloat16((v2 - mean) * inv * g[t + 512] + beta[t + 512]);
}

// ---------------------------------------------------------------------------
// Cast + transpose weights: W (768 x N f32, row-major) -> Wt (gridX*32 x 768 bf16)
// rows n >= N zero-filled. Grid: (rows/32, 768/32), block 256.
// ---------------------------------------------------------------------------
__global__ __launch_bounds__(256) void cast_transpose(
    const float* __restrict__ W, bf16* __restrict__ Wt, int N)
{
    __shared__ float t[32][33];
    int n0 = blockIdx.x * 32, k0 = blockIdx.y * 32;
    int tx = threadIdx.x & 31, ty = threadIdx.x >> 5;  // ty 0..7
    #pragma unroll
    for (int i = 0; i < 4; i++) {
        int k = k0 + ty + i * 8;
        int n = n0 + tx;
        t[ty + i * 8][tx] = (n < N) ? W[(size_t)k * N + n] : 0.f;
    }
    __syncthreads();
    #pragma unroll
    for (int i = 0; i < 4; i++) {
        int n = n0 + ty + i * 8;
        Wt[(size_t)n * K_DIM + k0 + tx] = __float2bfloat16(t[tx][ty + i * 8]);
    }
}

// ---------------------------------------------------------------------------
// MFMA bf16 GEMM: C(M,N) = A(M,768) @ Wt(N,768)^T + bias
// 128x128 tile, 256 threads (4 waves, 2x2 of 64x64), K-step 32.
// mode 0: bf16 store; mode 1: f32 store; mode 2: f32 = resid + gamma*(acc+bias)
// mode 3: f32 store, dual bias split at nsplit
// ---------------------------------------------------------------------------
__global__ __launch_bounds__(256) void mfma_gemm(
    const bf16*  __restrict__ A,
    const bf16*  __restrict__ Bt,
    const float* __restrict__ bias,
    void*        __restrict__ C,
    const float* __restrict__ resid,
    const float* __restrict__ gamma,
    const float* __restrict__ bias2,
    int M, int N, int mode, int nsplit)
{
    __shared__ __align__(16) char lds[16384];
    char* As = lds;
    char* Bs = lds + 8192;

    int tid  = threadIdx.x;
    int lane = tid & 63;
    int bm = blockIdx.y * 128, bn = blockIdx.x * 128;
    int wave = tid >> 6;
    int wr = (wave & 1) * 64, wc = (wave >> 1) * 64;

    ffrag acc[4][4] = {};

    int c0 = tid, c1 = tid + 256;
    int r0 = c0 >> 2, kb0 = (c0 & 3) * 8;
    int r1 = c1 >> 2, kb1 = (c1 & 3) * 8;
    int ra0 = min(bm + r0, M - 1), ra1 = min(bm + r1, M - 1);
    const bf16* gA0 = A  + (size_t)ra0 * K_DIM + kb0;
    const bf16* gA1 = A  + (size_t)ra1 * K_DIM + kb1;
    const bf16* gB0 = Bt + (size_t)(bn + r0) * K_DIM + kb0;
    const bf16* gB1 = Bt + (size_t)(bn + r1) * K_DIM + kb1;

    int mrow = lane & 15;
    int kq   = (lane >> 4) * 8;

    for (int k0 = 0; k0 < K_DIM; k0 += 32) {
        g2l16(gA0 + k0, As + c0 * 16);
        g2l16(gA1 + k0, As + c1 * 16);
        g2l16(gB0 + k0, Bs + c0 * 16);
        g2l16(gB1 + k0, Bs + c1 * 16);
        __syncthreads();
        bfrag a[4], b[4];
        #pragma unroll
        for (int t = 0; t < 4; t++) {
            a[t] = *(const bfrag*)(As + ((wr + t * 16 + mrow) * 32 + kq) * 2);
            b[t] = *(const bfrag*)(Bs + ((wc + t * 16 + mrow) * 32 + kq) * 2);
        }
        #pragma unroll
        for (int i = 0; i < 4; i++)
            #pragma unroll
            for (int j = 0; j < 4; j++)
                acc[i][j] = __builtin_amdgcn_mfma_f32_16x16x32_bf16(
                    a[i], b[j], acc[i][j], 0, 0, 0);
        __syncthreads();
    }

    int q4 = (lane >> 4) * 4;
    #pragma unroll
    for (int i = 0; i < 4; i++) {
        #pragma unroll
        for (int r = 0; r < 4; r++) {
            int rg = bm + wr + i * 16 + q4 + r;
            if (rg < M) {
                #pragma unroll
                for (int j = 0; j < 4; j++) {
                    int cg = bn + wc + j * 16 + mrow;
                    if (cg < N) {
                        float bv = (mode == 3 && cg >= nsplit) ? bias2[cg - nsplit]
                                                               : bias[cg];
                        float v = acc[i][j][r] + bv;
                        size_t idx = (size_t)rg * N + cg;
                        if (mode == 0)      ((bf16*)C)[idx]  = __float2bfloat16(v);
                        else if (mode == 2) ((float*)C)[idx] = resid[idx] + gamma[cg] * v;
                        else                ((float*)C)[idx] = v;
                    }
                }
            }
        }
    }
}

// ---------------------------------------------------------------------------
// Deformable sampling, corner-parallel:
// one wave per (b,q,h) unit; lane = corner-slot (lane>>3) x channel-octet (lane&7).
// Each lane loads 16B (8 bf16 channels) per corner; 6 load instrs cover all
// 12 samples x 4 corners. Cross-corner combine via 3 shfl_xor butterflies.
// comb (B*LQ, 432) f32: cols 0..287 = offsets, 288..431 = logits.
// ---------------------------------------------------------------------------
__global__ __launch_bounds__(256) void sample_kernel(
    const bf16*  __restrict__ value,
    const float* __restrict__ comb,
    bf16*        __restrict__ attn)
{
    int unit = __builtin_amdgcn_readfirstlane((blockIdx.x << 2) + (threadIdx.x >> 6));
    int lane = threadIdx.x & 63;
    int o   = lane & 7;          // channel octet -> channels o*8..o*8+7
    int c8  = lane >> 3;         // corner slot 0..7
    int k   = c8 & 3;            // dx = k&1, dy = k>>1
    int dx  = k & 1, dy = k >> 1;
    int h  = unit % NH;
    int bq = unit / NH;
    int q  = bq & (LQ - 1);
    int b  = bq >> 12;

    const float* rowp = comb + (size_t)bq * 432;
    const float* ob = rowp + h * 24;
    const float* lg = rowp + 288 + h * 12;

    // softmax over 12 (wave-uniform address -> scalar loads)
    float l[12];
    float mx = -1e30f;
    #pragma unroll
    for (int i = 0; i < 12; i++) { l[i] = lg[i]; mx = fmaxf(mx, l[i]); }
    float den = 0.f;
    #pragma unroll
    for (int i = 0; i < 12; i++) { l[i] = __expf(l[i] - mx); den += l[i]; }
    float rden = 1.f / den;
    #pragma unroll
    for (int i = 0; i < 12; i++) l[i] *= rden;

    float rx = ((q & 63) + 0.5f) * (1.f / 64.f);
    float ry = ((q >> 6) + 0.5f) * (1.f / 64.f);

    float acc[8] = {0.f};

    #pragma unroll
    for (int it = 0; it < 6; it++) {
        const int wl = (it < 2) ? 112 : (it < 4 ? 56 : 28);
        const int sl = (it < 2) ? 0   : (it < 4 ? 12544 : 15680);
        int s = it * 2 + ((lane >> 5) & 1);   // sample 0/1 of this pair
        float ox = ob[s * 2 + 0];
        float oy = ob[s * 2 + 1];
        float x = rx * wl + ox - 0.5f;
        float y = ry * wl + oy - 0.5f;
        float xf = floorf(x), yf = floorf(y);
        float wx = x - xf,  wy = y - yf;
        int xi = (int)xf + dx;
        int yi = (int)yf + dy;
        bool valid = ((unsigned)xi < (unsigned)wl) & ((unsigned)yi < (unsigned)wl);
        int xc = min(max(xi, 0), wl - 1);
        int yc = min(max(yi, 0), wl - 1);
        int cell = b * LIN + sl + yc * wl + xc;
        const uint4* vp = (const uint4*)(value + ((size_t)cell * NH + h) * HD + o * 8);
        uint4 v = *vp;
        float aw = (lane & 32) ? l[it * 2 + 1] : l[it * 2];
        float bw = (dx ? wx : 1.f - wx) * (dy ? wy : 1.f - wy);
        float w = valid ? aw * bw : 0.f;
        const unsigned* u = (const unsigned*)&v;
        #pragma unroll
        for (int j = 0; j < 4; j++) {
            float f0 = __uint_as_float(u[j] << 16);
            float f1 = __uint_as_float(u[j] & 0xFFFF0000u);
            acc[j * 2 + 0] = fmaf(w, f0, acc[j * 2 + 0]);
            acc[j * 2 + 1] = fmaf(w, f1, acc[j * 2 + 1]);
        }
    }

    // combine the 8 corner-slots (lanes with equal lane&7)
    #pragma unroll
    for (int m = 8; m <= 32; m <<= 1) {
        #pragma unroll
        for (int j = 0; j < 8; j++)
            acc[j] += __shfl_xor(acc[j], m);
    }

    if (c8 == 0) {
        union { bf16 h8[8]; uint4 u4; } r;
        #pragma unroll
        for (int j = 0; j < 8; j++) r.h8[j] = __float2bfloat16(acc[j]);
        *(uint4*)(attn + (size_t)bq * DM + h * HD + o * 8) = r.u4;
    }
}

// ---------------------------------------------------------------------------
extern "C" void kernel_launch(void* const* d_in, const int* in_sizes, int n_in,
                              void* d_out, int out_size, void* d_ws, size_t ws_size,
                              hipStream_t stream)
{
    const float* query  = (const float*)d_in[0];
    const float* feat   = (const float*)d_in[1];
    const float* ln_q_g = (const float*)d_in[2];
    const float* ln_q_b = (const float*)d_in[3];
    const float* ln_f_g = (const float*)d_in[4];
    const float* ln_f_b = (const float*)d_in[5];
    const float* W_off  = (const float*)d_in[6];
    const float* b_off  = (const float*)d_in[7];
    const float* W_attn = (const float*)d_in[8];
    const float* b_attn = (const float*)d_in[9];
    const float* W_val  = (const float*)d_in[10];
    const float* b_val  = (const float*)d_in[11];
    const float* W_out  = (const float*)d_in[12];
    const float* b_out  = (const float*)d_in[13];
    const float* gamma  = (const float*)d_in[14];
    float* out = (float*)d_out;

    char* ws = (char*)d_ws;
    char* od = (char*)d_out;
    const int M_F = BB * LIN;   // 65856
    const int M_Q = BB * LQ;    // 16384

    // ws layout (227,475,456 B proven):
    //   [0, 101,154,816)           value bf16 (65856 x 768)
    //   [101,154,816, 202,309,632) f_ln bf16; Wt_out overlays after value GEMM
    //   [202,309,632, 227,475,456) q_ln bf16; attn overlays after comb GEMM
    bf16*  value  = (bf16*)(ws);
    bf16*  f_ln   = (bf16*)(ws + 101154816);
    bf16*  Wt_out = (bf16*)(ws + 101154816);
    bf16*  q_ln   = (bf16*)(ws + 202309632);
    bf16*  attn   = (bf16*)(ws + 202309632);

    // d_out as scratch (50,331,648 B; dead before final GEMM):
    //   [0, 1,179,648)           Wt_val bf16 (768 x 768)
    //   [1,179,648, 1,966,080)   Wt_comb bf16 (512 x 768): rows 0..287 W_off,
    //                            288..431 W_attn, rest zero
    //   [2,162,688, 30,474,240)  comb f32 (16384 x 432)
    bf16*  Wt_val  = (bf16*)(od);
    bf16*  Wt_comb = (bf16*)(od + 1179648);
    float* comb    = (float*)(od + 2162688);

    // 1. weight cast/transpose
    cast_transpose<<<dim3(24, 24), 256, 0, stream>>>(W_val, Wt_val, 768);
    cast_transpose<<<dim3(9, 24), 256, 0, stream>>>(W_off, Wt_comb, 288);
    cast_transpose<<<dim3(7, 24), 256, 0, stream>>>(
        W_attn, Wt_comb + (size_t)288 * K_DIM, 144);  // rows 288..511 (zero-padded)

    // 2. LayerNorms
    ln_kernel<<<M_F, 256, 0, stream>>>(feat, ln_f_g, ln_f_b, f_ln);
    ln_kernel<<<M_Q, 256, 0, stream>>>(query, ln_q_g, ln_q_b, q_ln);

    // 3. value = f_ln @ W_val + b_val (bf16)
    mfma_gemm<<<dim3(6, (M_F + 127) / 128), 256, 0, stream>>>(
        f_ln, Wt_val, b_val, value, nullptr, nullptr, nullptr, M_F, DM, 0, 0);

    // 4. Wt_out into f_ln's (now dead) region
    cast_transpose<<<dim3(24, 24), 256, 0, stream>>>(W_out, Wt_out, 768);

    // 5. comb = q_ln @ [W_off | W_attn] + [b_off | b_attn] (f32, N=432)
    mfma_gemm<<<dim3(4, M_Q / 128), 256, 0, stream>>>(
        q_ln, Wt_comb, b_off, comb, nullptr, nullptr, b_attn, M_Q, 432, 3, 288);

    // 6. deformable sampling -> attn (bf16)
    sample_kernel<<<(M_Q * NH) / 4, 256, 0, stream>>>(value, comb, attn);

    // 7. out = query + gamma * (attn @ W_out + b_out)
    mfma_gemm<<<dim3(6, M_Q / 128), 256, 0, stream>>>(
        attn, Wt_out, b_out, out, query, gamma, nullptr, M_Q, DM, 2, 0);
}